// Round 1
// baseline (548.092 us; speedup 1.0000x reference)
//
#include <hip/hip_runtime.h>
#include <hip/hip_bf16.h>

typedef __hip_bfloat16 bf16;

#define NH   16
#define HD   128
#define SEQ  2048
#define BB   2
#define HID  2048

// ln(10000)/64
#define ROPE_C 0.14391156856f

using frag  = __attribute__((ext_vector_type(8))) short;   // 8 bf16 = 4 VGPRs
using f32x4 = __attribute__((ext_vector_type(4))) float;

// ---------- helpers ----------

// pack 8 fp32 -> 8 bf16 (one 16B LDS write)
__device__ __forceinline__ void cvt8_store(const float4 f0, const float4 f1, bf16* dst) {
    union { frag v; bf16 h[8]; } p;
    p.h[0] = __float2bfloat16(f0.x); p.h[1] = __float2bfloat16(f0.y);
    p.h[2] = __float2bfloat16(f0.z); p.h[3] = __float2bfloat16(f0.w);
    p.h[4] = __float2bfloat16(f1.x); p.h[5] = __float2bfloat16(f1.y);
    p.h[6] = __float2bfloat16(f1.z); p.h[7] = __float2bfloat16(f1.w);
    *reinterpret_cast<frag*>(dst) = p.v;
}

// pack 2 fp32 -> 1 dword of 2 bf16
__device__ __forceinline__ unsigned pk2(float a, float b) {
    union { bf16 h[2]; unsigned u; } p;
    p.h[0] = __float2bfloat16(a);
    p.h[1] = __float2bfloat16(b);
    return p.u;
}

// ---------- Q projection + fused RoPE (MFMA, unchanged) ----------
__global__ __launch_bounds__(256) void gemm_q_mfma(const float* __restrict__ A,
                                                   const float* __restrict__ W,
                                                   bf16* __restrict__ C) {
    __shared__ bf16 Asl[4096];
    __shared__ bf16 Bsl[4096];
    const int tid  = threadIdx.x;
    const int wave = tid >> 6;
    const int lane = tid & 63;
    const int quad = lane >> 4;
    const int l15  = lane & 15;
    const int row0 = blockIdx.y * 128;
    const int col0 = blockIdx.x * 128;   // = h*128

    const int n0 = tid, n1 = tid + 256;
    const int r0 = ((n0 >> 2) & 15) + ((n0 >> 6) << 4), c0 = (n0 & 3) * 8;
    const int r1 = ((n1 >> 2) & 15) + ((n1 >> 6) << 4), c1 = (n1 & 3) * 8;

    f32x4 acc[2][8];
#pragma unroll
    for (int i = 0; i < 2; ++i)
#pragma unroll
        for (int j = 0; j < 8; ++j) acc[i][j] = (f32x4){0.f,0.f,0.f,0.f};

    for (int k0 = 0; k0 < HID; k0 += 32) {
        __syncthreads();
        {
            const float4* a0 = reinterpret_cast<const float4*>(A + (size_t)(row0 + r0) * HID + k0 + c0);
            const float4* a1 = reinterpret_cast<const float4*>(A + (size_t)(row0 + r1) * HID + k0 + c1);
            const float4* b0 = reinterpret_cast<const float4*>(W + (size_t)(col0 + r0) * HID + k0 + c0);
            const float4* b1 = reinterpret_cast<const float4*>(W + (size_t)(col0 + r1) * HID + k0 + c1);
            cvt8_store(a0[0], a0[1], &Asl[n0 * 8]);
            cvt8_store(a1[0], a1[1], &Asl[n1 * 8]);
            cvt8_store(b0[0], b0[1], &Bsl[n0 * 8]);
            cvt8_store(b1[0], b1[1], &Bsl[n1 * 8]);
        }
        __syncthreads();
        frag af[2], bfr[8];
#pragma unroll
        for (int i = 0; i < 2; ++i)
            af[i] = *reinterpret_cast<const frag*>(&Asl[((((wave*2+i)*16 + l15)*4) + quad) * 8]);
#pragma unroll
        for (int j = 0; j < 8; ++j)
            bfr[j] = *reinterpret_cast<const frag*>(&Bsl[(((j*16 + l15)*4) + quad) * 8]);
#pragma unroll
        for (int i = 0; i < 2; ++i)
#pragma unroll
            for (int j = 0; j < 8; ++j)
                acc[i][j] = __builtin_amdgcn_mfma_f32_16x16x32_bf16(af[i], bfr[j], acc[i][j], 0, 0, 0);
    }

#pragma unroll
    for (int i = 0; i < 2; ++i)
#pragma unroll
        for (int r = 0; r < 4; ++r) {
            const int row = row0 + wave*32 + 16*i + quad*4 + r;
            const int s = row & (SEQ - 1);
            bf16* crow = C + (size_t)row * HID + col0;
#pragma unroll
            for (int j = 0; j < 4; ++j) {
                const int d = 16*j + l15;
                const float invf = expf(-(float)d * ROPE_C);
                float sn, cs;
                sincosf((float)s * invf, &sn, &cs);
                const float x1 = acc[i][j][r], x2 = acc[i][j+4][r];
                crow[d]      = __float2bfloat16(x1*cs - x2*sn);
                crow[d + 64] = __float2bfloat16(x2*cs + x1*sn);
            }
        }
}

// ---------- K/V projection (MFMA); K roped; fp32 outs + bf16 mirrors (unchanged) ----------
__global__ __launch_bounds__(256) void gemm_kv_mfma(const float* __restrict__ A,
                                                    const float* __restrict__ Wk,
                                                    const float* __restrict__ Wv,
                                                    float* __restrict__ Ck,
                                                    float* __restrict__ Cv,
                                                    bf16* __restrict__ kb,
                                                    bf16* __restrict__ vt) {
    __shared__ bf16 Asl[4096];
    __shared__ bf16 Bsl[4096];
    const int tid  = threadIdx.x;
    const int wave = tid >> 6;
    const int lane = tid & 63;
    const int quad = lane >> 4;
    const int l15  = lane & 15;
    const int row0 = blockIdx.y * 128;
    const bool is_v = (blockIdx.x != 0);
    const float* W = is_v ? Wv : Wk;

    const int n0 = tid, n1 = tid + 256;
    const int r0 = ((n0 >> 2) & 15) + ((n0 >> 6) << 4), c0 = (n0 & 3) * 8;
    const int r1 = ((n1 >> 2) & 15) + ((n1 >> 6) << 4), c1 = (n1 & 3) * 8;

    f32x4 acc[2][8];
#pragma unroll
    for (int i = 0; i < 2; ++i)
#pragma unroll
        for (int j = 0; j < 8; ++j) acc[i][j] = (f32x4){0.f,0.f,0.f,0.f};

    for (int k0 = 0; k0 < HID; k0 += 32) {
        __syncthreads();
        {
            const float4* a0 = reinterpret_cast<const float4*>(A + (size_t)(row0 + r0) * HID + k0 + c0);
            const float4* a1 = reinterpret_cast<const float4*>(A + (size_t)(row0 + r1) * HID + k0 + c1);
            const float4* b0 = reinterpret_cast<const float4*>(W + (size_t)r0 * HID + k0 + c0);
            const float4* b1 = reinterpret_cast<const float4*>(W + (size_t)r1 * HID + k0 + c1);
            cvt8_store(a0[0], a0[1], &Asl[n0 * 8]);
            cvt8_store(a1[0], a1[1], &Asl[n1 * 8]);
            cvt8_store(b0[0], b0[1], &Bsl[n0 * 8]);
            cvt8_store(b1[0], b1[1], &Bsl[n1 * 8]);
        }
        __syncthreads();
        frag af[2], bfr[8];
#pragma unroll
        for (int i = 0; i < 2; ++i)
            af[i] = *reinterpret_cast<const frag*>(&Asl[((((wave*2+i)*16 + l15)*4) + quad) * 8]);
#pragma unroll
        for (int j = 0; j < 8; ++j)
            bfr[j] = *reinterpret_cast<const frag*>(&Bsl[(((j*16 + l15)*4) + quad) * 8]);
#pragma unroll
        for (int i = 0; i < 2; ++i)
#pragma unroll
            for (int j = 0; j < 8; ++j)
                acc[i][j] = __builtin_amdgcn_mfma_f32_16x16x32_bf16(af[i], bfr[j], acc[i][j], 0, 0, 0);
    }

#pragma unroll
    for (int i = 0; i < 2; ++i)
#pragma unroll
        for (int r = 0; r < 4; ++r) {
            const int row = row0 + wave*32 + 16*i + quad*4 + r;   // b*SEQ + s
            const int s = row & (SEQ - 1);
            const int b = row >> 11;
            if (is_v) {
                float* crow = Cv + (size_t)row * HD;
#pragma unroll
                for (int j = 0; j < 8; ++j) {
                    const int d = 16*j + l15;
                    const float val = acc[i][j][r];
                    crow[d] = val;
                    vt[((size_t)b * HD + d) * SEQ + s] = __float2bfloat16(val);
                }
            } else {
                float* crow = Ck + (size_t)row * HD;
#pragma unroll
                for (int j = 0; j < 4; ++j) {
                    const int d = 16*j + l15;
                    const float invf = expf(-(float)d * ROPE_C);
                    float sn, cs;
                    sincosf((float)s * invf, &sn, &cs);
                    const float y1 = acc[i][j][r]*cs - acc[i][j+4][r]*sn;
                    const float y2 = acc[i][j+4][r]*cs + acc[i][j][r]*sn;
                    crow[d]      = y1;
                    crow[d + 64] = y2;
                    kb[(size_t)row * HD + d]      = __float2bfloat16(y1);
                    kb[(size_t)row * HD + d + 64] = __float2bfloat16(y2);
                }
            }
        }
}

// ---------- flash MFMA attention, S^T formulation ----------
// Round-10 changes vs round-9:
//  * pi-permuted V^T LDS layout: key at k-slot (h,quad,j) = 32h+16(j>>2)+4quad+(j&3)
//    -> the PV B-fragment is the lane's OWN packed p[t][r] dwords; the 32
//    ds_bpermute/tile/wave exchange network is deleted entirely.
//  * XOR bank swizzle (byte ^= ((byte>>7)&7)<<4) on both LDS tiles; swizzled
//    read base is chunk-independent (precomputed once, zero per-read VALU).
//  * async-STAGE split: next tile's K/V global loads issued into registers
//    before compute; ds_write after the post-compute barrier (T14).
//  * defer-max: skip O-rescale when tile max grew <= 90 raw (e^8 scaled; exact math).
__global__ __launch_bounds__(256) void attn_mfma(const bf16* __restrict__ qbuf,
                                                 const bf16* __restrict__ kb,
                                                 const bf16* __restrict__ vt,
                                                 bf16* __restrict__ attn_out) {
    __shared__ bf16 Ks[8192];   // 64 keys x 128 dims, chunked + swizzled
    __shared__ bf16 Vt[8192];   // 128 dims x 64 keys, pi-permuted + swizzled

    const int tid  = threadIdx.x;
    const int wave = tid >> 6;
    const int lane = tid & 63;
    const int quad = lane >> 4;
    const int l15  = lane & 15;
    const int q0   = blockIdx.x * 128;
    const int h    = blockIdx.y;
    const int b    = blockIdx.z;

    const bf16* kbb = kb + (size_t)b * SEQ * HD;
    const bf16* vtb = vt + (size_t)b * HD * SEQ;

    // Q B-operand frags: qfr[g][c] = Q[qrow=w*32+g*16+l15][dims c*32+quad*8..+7]
    frag qfr[2][4];
#pragma unroll
    for (int g = 0; g < 2; ++g) {
        const bf16* qrow = qbuf + ((size_t)(b * SEQ + q0 + wave * 32 + g * 16 + l15)) * HID + h * HD;
#pragma unroll
        for (int c = 0; c < 4; ++c)
            qfr[g][c] = *reinterpret_cast<const frag*>(qrow + c * 32 + quad * 8);
    }

    // K staging decode: 4 x 16B per thread (layout unchanged, + swizzle)
    int kkey[4], kdim[4], kof[4];
#pragma unroll
    for (int i = 0; i < 4; ++i) {
        const int n = tid + i * 256;
        kkey[i] = ((n >> 2) & 15) + (((n >> 6) & 3) << 4);
        kdim[i] = ((n >> 8) << 5) + ((n & 3) << 3);
        kof[i]  = (n * 16) ^ (((n >> 3) & 7) << 4);
    }
    // V staging decode: 8 x 8B per thread, pi-permuted key order + swizzle
    int vdim[8], vkey[8], vof[8];
#pragma unroll
    for (int i = 0; i < 8; ++i) {
        const int m = tid + i * 256;
        vdim[i] = ((m >> 8) << 4) + ((m >> 3) & 15);
        vkey[i] = (((m >> 7) & 1) << 5) + ((m & 1) << 4) + (((m >> 1) & 3) << 2);
        vof[i]  = (m * 8) ^ (((m >> 4) & 7) << 4);
    }

    // swizzled frag-read base (chunk-independent: chunk*1024 = 0 mod 1024)
    const int rb  = (l15 * 4 + quad) * 16;
    const int rbs = rb ^ (((rb >> 7) & 7) << 4);

    uint4 krg[4];
    uint2 vrg[8];

#define STAGE_LOAD(T0)                                                                               \
    {                                                                                                \
        _Pragma("unroll") for (int i = 0; i < 4; ++i)                                                \
            krg[i] = *reinterpret_cast<const uint4*>(kbb + (size_t)((T0) + kkey[i]) * HD + kdim[i]); \
        _Pragma("unroll") for (int i = 0; i < 8; ++i)                                                \
            vrg[i] = *reinterpret_cast<const uint2*>(vtb + (size_t)vdim[i] * SEQ + (T0) + vkey[i]);  \
    }
#define STAGE_WRITE()                                                                                \
    {                                                                                                \
        _Pragma("unroll") for (int i = 0; i < 4; ++i)                                                \
            *reinterpret_cast<uint4*>(reinterpret_cast<char*>(Ks) + kof[i]) = krg[i];                \
        _Pragma("unroll") for (int i = 0; i < 8; ++i)                                                \
            *reinterpret_cast<uint2*>(reinterpret_cast<char*>(Vt) + vof[i]) = vrg[i];                \
    }

    f32x4 oacc[2][8];
#pragma unroll
    for (int g = 0; g < 2; ++g)
#pragma unroll
        for (int dt = 0; dt < 8; ++dt) oacc[g][dt] = (f32x4){0.f, 0.f, 0.f, 0.f};
    float mrow[2] = {-1e30f, -1e30f};
    float lrow[2] = {0.f, 0.f};
    const float sl2 = 0.12751722f;   // (1/sqrt(128)) * log2(e)

    // prologue: stage tile 0
    STAGE_LOAD(0);
    STAGE_WRITE();
    __syncthreads();

    for (int t0 = 0; t0 < SEQ; t0 += 64) {
        const int tn = t0 + 64;
        if (tn < SEQ) STAGE_LOAD(tn);   // in-flight across compute

        // S^T: sacc[g][t], rows = keys t*16+quad*4+r, col = qrow l15
        f32x4 sacc[2][4];
#pragma unroll
        for (int g = 0; g < 2; ++g)
#pragma unroll
            for (int t = 0; t < 4; ++t) sacc[g][t] = (f32x4){0.f,0.f,0.f,0.f};
#pragma unroll
        for (int c = 0; c < 4; ++c) {
            frag kf[4];
#pragma unroll
            for (int t = 0; t < 4; ++t)
                kf[t] = *reinterpret_cast<const frag*>(
                            reinterpret_cast<const char*>(Ks) + (c*4+t)*1024 + rbs);
#pragma unroll
            for (int g = 0; g < 2; ++g)
#pragma unroll
                for (int t = 0; t < 4; ++t)
                    sacc[g][t] = __builtin_amdgcn_mfma_f32_16x16x32_bf16(kf[t], qfr[g][c], sacc[g][t], 0, 0, 0);
        }

        // softmax; P^T B-frags are lane-local (pi-permuted PV key order)
        float al[2];
        bool  skip[2];
        frag  pb[2][2];
#pragma unroll
        for (int g = 0; g < 2; ++g) {
            float mx = -1e30f;
#pragma unroll
            for (int t = 0; t < 4; ++t)
#pragma unroll
                for (int r = 0; r < 4; ++r) mx = fmaxf(mx, sacc[g][t][r]);
            mx = fmaxf(mx, __shfl_xor(mx, 16));
            mx = fmaxf(mx, __shfl_xor(mx, 32));
            skip[g] = (bool)__all(mx - mrow[g] <= 90.0f);   // e^(90*scale) ~ e^8 bound
            const float mn = skip[g] ? mrow[g] : fmaxf(mrow[g], mx);
            al[g] = skip[g] ? 1.f : exp2f((mrow[g] - mn) * sl2);
            const float mnc = mn * sl2;
            float p[4][4];
            float ps = 0.f;
#pragma unroll
            for (int t = 0; t < 4; ++t)
#pragma unroll
                for (int r = 0; r < 4; ++r) {
                    p[t][r] = exp2f(fmaf(sacc[g][t][r], sl2, -mnc));
                    ps += p[t][r];
                }
            ps += __shfl_xor(ps, 16);
            ps += __shfl_xor(ps, 32);
            lrow[g] = lrow[g] * al[g] + ps;
            mrow[g] = mn;

            // pb[g][hh] element j = key 32*hh + 16*(j>>2) + 4*quad + (j&3)
            //                     = p[2*hh + (j>>2)][j&3]  -- own registers, no shuffle
#pragma unroll
            for (int hh = 0; hh < 2; ++hh) {
                union { unsigned u[4]; frag f; } pf;
                pf.u[0] = pk2(p[2*hh][0],   p[2*hh][1]);
                pf.u[1] = pk2(p[2*hh][2],   p[2*hh][3]);
                pf.u[2] = pk2(p[2*hh+1][0], p[2*hh+1][1]);
                pf.u[3] = pk2(p[2*hh+1][2], p[2*hh+1][3]);
                pb[g][hh] = pf.f;
            }
        }

        // rescale O^T accumulators (skipped when max growth deferred)
#pragma unroll
        for (int g = 0; g < 2; ++g)
            if (!skip[g])
#pragma unroll
                for (int dt = 0; dt < 8; ++dt)
#pragma unroll
                    for (int r = 0; r < 4; ++r) oacc[g][dt][r] *= al[g];

        // O^T += V^T P^T   (V^T LDS already in pi key order)
#pragma unroll
        for (int dt = 0; dt < 8; ++dt) {
            frag v0 = *reinterpret_cast<const frag*>(
                          reinterpret_cast<const char*>(Vt) + (dt*2+0)*1024 + rbs);
            frag v1 = *reinterpret_cast<const frag*>(
                          reinterpret_cast<const char*>(Vt) + (dt*2+1)*1024 + rbs);
#pragma unroll
            for (int g = 0; g < 2; ++g) {
                oacc[g][dt] = __builtin_amdgcn_mfma_f32_16x16x32_bf16(v0, pb[g][0], oacc[g][dt], 0, 0, 0);
                oacc[g][dt] = __builtin_amdgcn_mfma_f32_16x16x32_bf16(v1, pb[g][1], oacc[g][dt], 0, 0, 0);
            }
        }

        __syncthreads();
        if (tn < SEQ) STAGE_WRITE();
        __syncthreads();
    }
#undef STAGE_LOAD
#undef STAGE_WRITE

    // epilogue: O^T lane(quad,l15) holds qrow=w*32+g*16+l15, dims dt*16+quad*4+r
#pragma unroll
    for (int g = 0; g < 2; ++g) {
        const float inv = 1.f / lrow[g];
        const int s = q0 + wave * 32 + g * 16 + l15;
        bf16* orow = attn_out + ((size_t)(b * SEQ + s)) * HID + h * HD;
#pragma unroll
        for (int dt = 0; dt < 8; ++dt) {
            uint2 val;
            val.x = pk2(oacc[g][dt][0] * inv, oacc[g][dt][1] * inv);
            val.y = pk2(oacc[g][dt][2] * inv, oacc[g][dt][3] * inv);
            *reinterpret_cast<uint2*>(orow + dt * 16 + quad * 4) = val;
        }
    }
}

// ---------- final projection (MFMA, unchanged): C(f32) = A(bf16) * Wo(f32)^T ----------
__global__ __launch_bounds__(256) void gemm_o_mfma(const bf16* __restrict__ A,
                                                   const float* __restrict__ W,
                                                   float* __restrict__ C) {
    __shared__ bf16 Asl[4096];
    __shared__ bf16 Bsl[4096];
    const int tid  = threadIdx.x;
    const int wave = tid >> 6;
    const int lane = tid & 63;
    const int quad = lane >> 4;
    const int l15  = lane & 15;
    const int row0 = blockIdx.y * 128;
    const int col0 = blockIdx.x * 128;

    const int n0 = tid, n1 = tid + 256;
    const int r0 = ((n0 >> 2) & 15) + ((n0 >> 6) << 4), c0 = (n0 & 3) * 8;
    const int r1 = ((n1 >> 2) & 15) + ((n1 >> 6) << 4), c1 = (n1 & 3) * 8;

    f32x4 acc[2][8];
#pragma unroll
    for (int i = 0; i < 2; ++i)
#pragma unroll
        for (int j = 0; j < 8; ++j) acc[i][j] = (f32x4){0.f,0.f,0.f,0.f};

    for (int k0 = 0; k0 < HID; k0 += 32) {
        __syncthreads();
        {
            *reinterpret_cast<uint4*>(&Asl[n0 * 8]) =
                *reinterpret_cast<const uint4*>(A + (size_t)(row0 + r0) * HID + k0 + c0);
            *reinterpret_cast<uint4*>(&Asl[n1 * 8]) =
                *reinterpret_cast<const uint4*>(A + (size_t)(row0 + r1) * HID + k0 + c1);
            const float4* b0 = reinterpret_cast<const float4*>(W + (size_t)(col0 + r0) * HID + k0 + c0);
            const float4* b1 = reinterpret_cast<const float4*>(W + (size_t)(col0 + r1) * HID + k0 + c1);
            cvt8_store(b0[0], b0[1], &Bsl[n0 * 8]);
            cvt8_store(b1[0], b1[1], &Bsl[n1 * 8]);
        }
        __syncthreads();
        frag af[2], bfr[8];
#pragma unroll
        for (int i = 0; i < 2; ++i)
            af[i] = *reinterpret_cast<const frag*>(&Asl[((((wave*2+i)*16 + l15)*4) + quad) * 8]);
#pragma unroll
        for (int j = 0; j < 8; ++j)
            bfr[j] = *reinterpret_cast<const frag*>(&Bsl[(((j*16 + l15)*4) + quad) * 8]);
#pragma unroll
        for (int i = 0; i < 2; ++i)
#pragma unroll
            for (int j = 0; j < 8; ++j)
                acc[i][j] = __builtin_amdgcn_mfma_f32_16x16x32_bf16(af[i], bfr[j], acc[i][j], 0, 0, 0);
    }

#pragma unroll
    for (int i = 0; i < 2; ++i)
#pragma unroll
        for (int r = 0; r < 4; ++r) {
            const int row = row0 + wave*32 + 16*i + quad*4 + r;
            float* crow = C + (size_t)row * HID + col0;
#pragma unroll
            for (int j = 0; j < 8; ++j)
                crow[16*j + l15] = acc[i][j][r];
        }
}

// ---------- launch ----------
extern "C" void kernel_launch(void* const* d_in, const int* in_sizes, int n_in,
                              void* d_out, int out_size, void* d_ws, size_t ws_size,
                              hipStream_t stream) {
    const float* hs = (const float*)d_in[0];
    const float* Wq = (const float*)d_in[1];
    const float* Wk = (const float*)d_in[2];
    const float* Wv = (const float*)d_in[3];
    const float* Wo = (const float*)d_in[4];

    float* out      = (float*)d_out;
    float* out_attn = out;                         // [B,S,H]    8388608 f32 (33.55 MB)
    float* out_k    = out + 8388608;               // [B,1,S,HD]  524288 f32
    float* out_v    = out + 8388608 + 524288;      // [B,1,S,HD]  524288 f32

    // Scratch inside d_out's attn region (consumed before gemm_o_mfma writes it):
    bf16* qbuf = (bf16*)d_out;                     // bytes 0..16.78M  roped q bf16
    bf16* kb   = (bf16*)((char*)d_out + 16777216); // bytes ..17.83M   roped k bf16
    bf16* vt   = (bf16*)((char*)d_out + 17825792); // bytes ..18.87M   v^T bf16
    bf16* attn_out = (bf16*)d_ws;                  // [B,S,H] bf16, 16.78 MB

    dim3 blk(256);
    gemm_q_mfma <<<dim3(HID/128, (BB*SEQ)/128), blk, 0, stream>>>(hs, Wq, qbuf);
    gemm_kv_mfma<<<dim3(2,       (BB*SEQ)/128), blk, 0, stream>>>(hs, Wk, Wv, out_k, out_v, kb, vt);
    attn_mfma   <<<dim3(SEQ/128, NH, BB),       blk, 0, stream>>>(qbuf, kb, vt, attn_out);
    gemm_o_mfma <<<dim3(HID/128, (BB*SEQ)/128), blk, 0, stream>>>(attn_out, Wo, out_attn);
}

// Round 2
// 482.481 us; speedup vs baseline: 1.1360x; 1.1360x over previous
//
#include <hip/hip_runtime.h>
#include <hip/hip_bf16.h>

typedef __hip_bfloat16 bf16;

#define NH   16
#define HD   128
#define SEQ  2048
#define BB   2
#define HID  2048

// ln(10000)/64
#define ROPE_C 0.14391156856f

using frag  = __attribute__((ext_vector_type(8))) short;   // 8 bf16 = 4 VGPRs
using f32x4 = __attribute__((ext_vector_type(4))) float;

// ---------- helpers ----------

// pack 8 fp32 -> 8 bf16 (one 16B LDS write)
__device__ __forceinline__ void cvt8_store(const float4 f0, const float4 f1, bf16* dst) {
    union { frag v; bf16 h[8]; } p;
    p.h[0] = __float2bfloat16(f0.x); p.h[1] = __float2bfloat16(f0.y);
    p.h[2] = __float2bfloat16(f0.z); p.h[3] = __float2bfloat16(f0.w);
    p.h[4] = __float2bfloat16(f1.x); p.h[5] = __float2bfloat16(f1.y);
    p.h[6] = __float2bfloat16(f1.z); p.h[7] = __float2bfloat16(f1.w);
    *reinterpret_cast<frag*>(dst) = p.v;
}

// pack 2 fp32 -> 1 dword of 2 bf16
__device__ __forceinline__ unsigned pk2(float a, float b) {
    union { bf16 h[2]; unsigned u; } p;
    p.h[0] = __float2bfloat16(a);
    p.h[1] = __float2bfloat16(b);
    return p.u;
}

// ---------- Q projection + fused RoPE (MFMA, unchanged) ----------
__global__ __launch_bounds__(256) void gemm_q_mfma(const float* __restrict__ A,
                                                   const float* __restrict__ W,
                                                   bf16* __restrict__ C) {
    __shared__ bf16 Asl[4096];
    __shared__ bf16 Bsl[4096];
    const int tid  = threadIdx.x;
    const int wave = tid >> 6;
    const int lane = tid & 63;
    const int quad = lane >> 4;
    const int l15  = lane & 15;
    const int row0 = blockIdx.y * 128;
    const int col0 = blockIdx.x * 128;   // = h*128

    const int n0 = tid, n1 = tid + 256;
    const int r0 = ((n0 >> 2) & 15) + ((n0 >> 6) << 4), c0 = (n0 & 3) * 8;
    const int r1 = ((n1 >> 2) & 15) + ((n1 >> 6) << 4), c1 = (n1 & 3) * 8;

    f32x4 acc[2][8];
#pragma unroll
    for (int i = 0; i < 2; ++i)
#pragma unroll
        for (int j = 0; j < 8; ++j) acc[i][j] = (f32x4){0.f,0.f,0.f,0.f};

    for (int k0 = 0; k0 < HID; k0 += 32) {
        __syncthreads();
        {
            const float4* a0 = reinterpret_cast<const float4*>(A + (size_t)(row0 + r0) * HID + k0 + c0);
            const float4* a1 = reinterpret_cast<const float4*>(A + (size_t)(row0 + r1) * HID + k0 + c1);
            const float4* b0 = reinterpret_cast<const float4*>(W + (size_t)(col0 + r0) * HID + k0 + c0);
            const float4* b1 = reinterpret_cast<const float4*>(W + (size_t)(col0 + r1) * HID + k0 + c1);
            cvt8_store(a0[0], a0[1], &Asl[n0 * 8]);
            cvt8_store(a1[0], a1[1], &Asl[n1 * 8]);
            cvt8_store(b0[0], b0[1], &Bsl[n0 * 8]);
            cvt8_store(b1[0], b1[1], &Bsl[n1 * 8]);
        }
        __syncthreads();
        frag af[2], bfr[8];
#pragma unroll
        for (int i = 0; i < 2; ++i)
            af[i] = *reinterpret_cast<const frag*>(&Asl[((((wave*2+i)*16 + l15)*4) + quad) * 8]);
#pragma unroll
        for (int j = 0; j < 8; ++j)
            bfr[j] = *reinterpret_cast<const frag*>(&Bsl[(((j*16 + l15)*4) + quad) * 8]);
#pragma unroll
        for (int i = 0; i < 2; ++i)
#pragma unroll
            for (int j = 0; j < 8; ++j)
                acc[i][j] = __builtin_amdgcn_mfma_f32_16x16x32_bf16(af[i], bfr[j], acc[i][j], 0, 0, 0);
    }

#pragma unroll
    for (int i = 0; i < 2; ++i)
#pragma unroll
        for (int r = 0; r < 4; ++r) {
            const int row = row0 + wave*32 + 16*i + quad*4 + r;
            const int s = row & (SEQ - 1);
            bf16* crow = C + (size_t)row * HID + col0;
#pragma unroll
            for (int j = 0; j < 4; ++j) {
                const int d = 16*j + l15;
                const float invf = expf(-(float)d * ROPE_C);
                float sn, cs;
                sincosf((float)s * invf, &sn, &cs);
                const float x1 = acc[i][j][r], x2 = acc[i][j+4][r];
                crow[d]      = __float2bfloat16(x1*cs - x2*sn);
                crow[d + 64] = __float2bfloat16(x2*cs + x1*sn);
            }
        }
}

// ---------- K/V projection (MFMA); K roped; fp32 outs + bf16 mirrors (unchanged) ----------
__global__ __launch_bounds__(256) void gemm_kv_mfma(const float* __restrict__ A,
                                                    const float* __restrict__ Wk,
                                                    const float* __restrict__ Wv,
                                                    float* __restrict__ Ck,
                                                    float* __restrict__ Cv,
                                                    bf16* __restrict__ kb,
                                                    bf16* __restrict__ vt) {
    __shared__ bf16 Asl[4096];
    __shared__ bf16 Bsl[4096];
    const int tid  = threadIdx.x;
    const int wave = tid >> 6;
    const int lane = tid & 63;
    const int quad = lane >> 4;
    const int l15  = lane & 15;
    const int row0 = blockIdx.y * 128;
    const bool is_v = (blockIdx.x != 0);
    const float* W = is_v ? Wv : Wk;

    const int n0 = tid, n1 = tid + 256;
    const int r0 = ((n0 >> 2) & 15) + ((n0 >> 6) << 4), c0 = (n0 & 3) * 8;
    const int r1 = ((n1 >> 2) & 15) + ((n1 >> 6) << 4), c1 = (n1 & 3) * 8;

    f32x4 acc[2][8];
#pragma unroll
    for (int i = 0; i < 2; ++i)
#pragma unroll
        for (int j = 0; j < 8; ++j) acc[i][j] = (f32x4){0.f,0.f,0.f,0.f};

    for (int k0 = 0; k0 < HID; k0 += 32) {
        __syncthreads();
        {
            const float4* a0 = reinterpret_cast<const float4*>(A + (size_t)(row0 + r0) * HID + k0 + c0);
            const float4* a1 = reinterpret_cast<const float4*>(A + (size_t)(row0 + r1) * HID + k0 + c1);
            const float4* b0 = reinterpret_cast<const float4*>(W + (size_t)r0 * HID + k0 + c0);
            const float4* b1 = reinterpret_cast<const float4*>(W + (size_t)r1 * HID + k0 + c1);
            cvt8_store(a0[0], a0[1], &Asl[n0 * 8]);
            cvt8_store(a1[0], a1[1], &Asl[n1 * 8]);
            cvt8_store(b0[0], b0[1], &Bsl[n0 * 8]);
            cvt8_store(b1[0], b1[1], &Bsl[n1 * 8]);
        }
        __syncthreads();
        frag af[2], bfr[8];
#pragma unroll
        for (int i = 0; i < 2; ++i)
            af[i] = *reinterpret_cast<const frag*>(&Asl[((((wave*2+i)*16 + l15)*4) + quad) * 8]);
#pragma unroll
        for (int j = 0; j < 8; ++j)
            bfr[j] = *reinterpret_cast<const frag*>(&Bsl[(((j*16 + l15)*4) + quad) * 8]);
#pragma unroll
        for (int i = 0; i < 2; ++i)
#pragma unroll
            for (int j = 0; j < 8; ++j)
                acc[i][j] = __builtin_amdgcn_mfma_f32_16x16x32_bf16(af[i], bfr[j], acc[i][j], 0, 0, 0);
    }

#pragma unroll
    for (int i = 0; i < 2; ++i)
#pragma unroll
        for (int r = 0; r < 4; ++r) {
            const int row = row0 + wave*32 + 16*i + quad*4 + r;   // b*SEQ + s
            const int s = row & (SEQ - 1);
            const int b = row >> 11;
            if (is_v) {
                float* crow = Cv + (size_t)row * HD;
#pragma unroll
                for (int j = 0; j < 8; ++j) {
                    const int d = 16*j + l15;
                    const float val = acc[i][j][r];
                    crow[d] = val;
                    vt[((size_t)b * HD + d) * SEQ + s] = __float2bfloat16(val);
                }
            } else {
                float* crow = Ck + (size_t)row * HD;
#pragma unroll
                for (int j = 0; j < 4; ++j) {
                    const int d = 16*j + l15;
                    const float invf = expf(-(float)d * ROPE_C);
                    float sn, cs;
                    sincosf((float)s * invf, &sn, &cs);
                    const float y1 = acc[i][j][r]*cs - acc[i][j+4][r]*sn;
                    const float y2 = acc[i][j+4][r]*cs + acc[i][j][r]*sn;
                    crow[d]      = y1;
                    crow[d + 64] = y2;
                    kb[(size_t)row * HD + d]      = __float2bfloat16(y1);
                    kb[(size_t)row * HD + d + 64] = __float2bfloat16(y2);
                }
            }
        }
}

// ---------- flash MFMA attention, S^T formulation ----------
// Round-11: 64-q-row blocks (1024 blocks = 4/CU, 16 waves/CU) to attack the
// latency-bound regime (was 2 blocks/CU, MfmaUtil 13%, VALUBusy 30%).
// Synchronous stage-between-barriers restored (T14 reg-residency regressed).
// Kept from round-10: pi-permuted V^T (zero-shuffle PV), XOR bank swizzle
// (conflicts 1.26e7 -> 0), defer-max rescale skip. __expf restored.
__global__ __launch_bounds__(256) void attn_mfma(const bf16* __restrict__ qbuf,
                                                 const bf16* __restrict__ kb,
                                                 const bf16* __restrict__ vt,
                                                 bf16* __restrict__ attn_out) {
    __shared__ bf16 Ks[8192];   // 64 keys x 128 dims, chunked + swizzled
    __shared__ bf16 Vt[8192];   // 128 dims x 64 keys, pi-permuted + swizzled

    const int tid  = threadIdx.x;
    const int wave = tid >> 6;
    const int lane = tid & 63;
    const int quad = lane >> 4;
    const int l15  = lane & 15;
    const int q0   = blockIdx.x * 64;
    const int h    = blockIdx.y;
    const int b    = blockIdx.z;

    const bf16* kbb = kb + (size_t)b * SEQ * HD;
    const bf16* vtb = vt + (size_t)b * HD * SEQ;

    // Q B-operand frags: qfr[c] = Q[qrow=w*16+l15][dims c*32+quad*8..+7]
    frag qfr[4];
    {
        const bf16* qrow = qbuf + ((size_t)(b * SEQ + q0 + wave * 16 + l15)) * HID + h * HD;
#pragma unroll
        for (int c = 0; c < 4; ++c)
            qfr[c] = *reinterpret_cast<const frag*>(qrow + c * 32 + quad * 8);
    }

    // K staging decode: 4 x 16B per thread + swizzle
    int kkey[4], kdim[4], kof[4];
#pragma unroll
    for (int i = 0; i < 4; ++i) {
        const int n = tid + i * 256;
        kkey[i] = ((n >> 2) & 15) + (((n >> 6) & 3) << 4);
        kdim[i] = ((n >> 8) << 5) + ((n & 3) << 3);
        kof[i]  = (n * 16) ^ (((n >> 3) & 7) << 4);
    }
    // V staging decode: 8 x 8B per thread, pi-permuted key order + swizzle
    int vdim[8], vkey[8], vof[8];
#pragma unroll
    for (int i = 0; i < 8; ++i) {
        const int m = tid + i * 256;
        vdim[i] = ((m >> 8) << 4) + ((m >> 3) & 15);
        vkey[i] = (((m >> 7) & 1) << 5) + ((m & 1) << 4) + (((m >> 1) & 3) << 2);
        vof[i]  = (m * 8) ^ (((m >> 4) & 7) << 4);
    }

    // swizzled frag-read base (chunk-independent: chunk*1024 = 0 mod 1024)
    const int rb  = (l15 * 4 + quad) * 16;
    const int rbs = rb ^ (((rb >> 7) & 7) << 4);

    f32x4 oacc[8];
#pragma unroll
    for (int dt = 0; dt < 8; ++dt) oacc[dt] = (f32x4){0.f, 0.f, 0.f, 0.f};
    float mrow = -1e30f;
    float lrow = 0.f;
    const float scale = 0.088388347648318433f;   // 1/sqrt(128)

    for (int t0 = 0; t0 < SEQ; t0 += 64) {
        __syncthreads();
        {
            uint4 krg[4];
            uint2 vrg[8];
#pragma unroll
            for (int i = 0; i < 4; ++i)
                krg[i] = *reinterpret_cast<const uint4*>(kbb + (size_t)(t0 + kkey[i]) * HD + kdim[i]);
#pragma unroll
            for (int i = 0; i < 8; ++i)
                vrg[i] = *reinterpret_cast<const uint2*>(vtb + (size_t)vdim[i] * SEQ + t0 + vkey[i]);
#pragma unroll
            for (int i = 0; i < 4; ++i)
                *reinterpret_cast<uint4*>(reinterpret_cast<char*>(Ks) + kof[i]) = krg[i];
#pragma unroll
            for (int i = 0; i < 8; ++i)
                *reinterpret_cast<uint2*>(reinterpret_cast<char*>(Vt) + vof[i]) = vrg[i];
        }
        __syncthreads();

        // S^T: sacc[t], rows = keys t*16+quad*4+r, col = qrow l15
        f32x4 sacc[4];
#pragma unroll
        for (int t = 0; t < 4; ++t) sacc[t] = (f32x4){0.f,0.f,0.f,0.f};
#pragma unroll
        for (int c = 0; c < 4; ++c) {
            frag kf[4];
#pragma unroll
            for (int t = 0; t < 4; ++t)
                kf[t] = *reinterpret_cast<const frag*>(
                            reinterpret_cast<const char*>(Ks) + (c*4+t)*1024 + rbs);
#pragma unroll
            for (int t = 0; t < 4; ++t)
                sacc[t] = __builtin_amdgcn_mfma_f32_16x16x32_bf16(kf[t], qfr[c], sacc[t], 0, 0, 0);
        }

        // softmax; P^T B-frags are lane-local (pi-permuted PV key order)
        float mx = -1e30f;
#pragma unroll
        for (int t = 0; t < 4; ++t)
#pragma unroll
            for (int r = 0; r < 4; ++r) mx = fmaxf(mx, sacc[t][r]);
        mx = fmaxf(mx, __shfl_xor(mx, 16));
        mx = fmaxf(mx, __shfl_xor(mx, 32));
        const bool skip = (bool)__all(mx - mrow <= 90.0f);   // e^(90*scale) ~ e^8 bound
        const float mn = skip ? mrow : fmaxf(mrow, mx);
        const float al = skip ? 1.f : __expf((mrow - mn) * scale);
        float p[4][4];
        float ps = 0.f;
#pragma unroll
        for (int t = 0; t < 4; ++t)
#pragma unroll
            for (int r = 0; r < 4; ++r) {
                p[t][r] = __expf((sacc[t][r] - mn) * scale);
                ps += p[t][r];
            }
        ps += __shfl_xor(ps, 16);
        ps += __shfl_xor(ps, 32);
        lrow = lrow * al + ps;
        mrow = mn;

        // pb[hh] element j = key 32*hh + 16*(j>>2) + 4*quad + (j&3)
        //                  = p[2*hh + (j>>2)][j&3]  -- own registers, no shuffle
        frag pb[2];
#pragma unroll
        for (int hh = 0; hh < 2; ++hh) {
            union { unsigned u[4]; frag f; } pf;
            pf.u[0] = pk2(p[2*hh][0],   p[2*hh][1]);
            pf.u[1] = pk2(p[2*hh][2],   p[2*hh][3]);
            pf.u[2] = pk2(p[2*hh+1][0], p[2*hh+1][1]);
            pf.u[3] = pk2(p[2*hh+1][2], p[2*hh+1][3]);
            pb[hh] = pf.f;
        }

        // rescale O^T accumulators (skipped when max growth deferred)
        if (!skip)
#pragma unroll
            for (int dt = 0; dt < 8; ++dt)
#pragma unroll
                for (int r = 0; r < 4; ++r) oacc[dt][r] *= al;

        // O^T += V^T P^T   (V^T LDS already in pi key order)
#pragma unroll
        for (int dt = 0; dt < 8; ++dt) {
            frag v0 = *reinterpret_cast<const frag*>(
                          reinterpret_cast<const char*>(Vt) + (dt*2+0)*1024 + rbs);
            frag v1 = *reinterpret_cast<const frag*>(
                          reinterpret_cast<const char*>(Vt) + (dt*2+1)*1024 + rbs);
            oacc[dt] = __builtin_amdgcn_mfma_f32_16x16x32_bf16(v0, pb[0], oacc[dt], 0, 0, 0);
            oacc[dt] = __builtin_amdgcn_mfma_f32_16x16x32_bf16(v1, pb[1], oacc[dt], 0, 0, 0);
        }
    }

    // epilogue: O^T lane(quad,l15) holds qrow=w*16+l15, dims dt*16+quad*4+r
    {
        const float inv = 1.f / lrow;
        const int s = q0 + wave * 16 + l15;
        bf16* orow = attn_out + ((size_t)(b * SEQ + s)) * HID + h * HD;
#pragma unroll
        for (int dt = 0; dt < 8; ++dt) {
            uint2 val;
            val.x = pk2(oacc[dt][0] * inv, oacc[dt][1] * inv);
            val.y = pk2(oacc[dt][2] * inv, oacc[dt][3] * inv);
            *reinterpret_cast<uint2*>(orow + dt * 16 + quad * 4) = val;
        }
    }
}

// ---------- final projection (MFMA, unchanged): C(f32) = A(bf16) * Wo(f32)^T ----------
__global__ __launch_bounds__(256) void gemm_o_mfma(const bf16* __restrict__ A,
                                                   const float* __restrict__ W,
                                                   float* __restrict__ C) {
    __shared__ bf16 Asl[4096];
    __shared__ bf16 Bsl[4096];
    const int tid  = threadIdx.x;
    const int wave = tid >> 6;
    const int lane = tid & 63;
    const int quad = lane >> 4;
    const int l15  = lane & 15;
    const int row0 = blockIdx.y * 128;
    const int col0 = blockIdx.x * 128;

    const int n0 = tid, n1 = tid + 256;
    const int r0 = ((n0 >> 2) & 15) + ((n0 >> 6) << 4), c0 = (n0 & 3) * 8;
    const int r1 = ((n1 >> 2) & 15) + ((n1 >> 6) << 4), c1 = (n1 & 3) * 8;

    f32x4 acc[2][8];
#pragma unroll
    for (int i = 0; i < 2; ++i)
#pragma unroll
        for (int j = 0; j < 8; ++j) acc[i][j] = (f32x4){0.f,0.f,0.f,0.f};

    for (int k0 = 0; k0 < HID; k0 += 32) {
        __syncthreads();
        {
            *reinterpret_cast<uint4*>(&Asl[n0 * 8]) =
                *reinterpret_cast<const uint4*>(A + (size_t)(row0 + r0) * HID + k0 + c0);
            *reinterpret_cast<uint4*>(&Asl[n1 * 8]) =
                *reinterpret_cast<const uint4*>(A + (size_t)(row0 + r1) * HID + k0 + c1);
            const float4* b0 = reinterpret_cast<const float4*>(W + (size_t)(col0 + r0) * HID + k0 + c0);
            const float4* b1 = reinterpret_cast<const float4*>(W + (size_t)(col0 + r1) * HID + k0 + c1);
            cvt8_store(b0[0], b0[1], &Bsl[n0 * 8]);
            cvt8_store(b1[0], b1[1], &Bsl[n1 * 8]);
        }
        __syncthreads();
        frag af[2], bfr[8];
#pragma unroll
        for (int i = 0; i < 2; ++i)
            af[i] = *reinterpret_cast<const frag*>(&Asl[((((wave*2+i)*16 + l15)*4) + quad) * 8]);
#pragma unroll
        for (int j = 0; j < 8; ++j)
            bfr[j] = *reinterpret_cast<const frag*>(&Bsl[(((j*16 + l15)*4) + quad) * 8]);
#pragma unroll
        for (int i = 0; i < 2; ++i)
#pragma unroll
            for (int j = 0; j < 8; ++j)
                acc[i][j] = __builtin_amdgcn_mfma_f32_16x16x32_bf16(af[i], bfr[j], acc[i][j], 0, 0, 0);
    }

#pragma unroll
    for (int i = 0; i < 2; ++i)
#pragma unroll
        for (int r = 0; r < 4; ++r) {
            const int row = row0 + wave*32 + 16*i + quad*4 + r;
            float* crow = C + (size_t)row * HID + col0;
#pragma unroll
            for (int j = 0; j < 8; ++j)
                crow[16*j + l15] = acc[i][j][r];
        }
}

// ---------- launch ----------
extern "C" void kernel_launch(void* const* d_in, const int* in_sizes, int n_in,
                              void* d_out, int out_size, void* d_ws, size_t ws_size,
                              hipStream_t stream) {
    const float* hs = (const float*)d_in[0];
    const float* Wq = (const float*)d_in[1];
    const float* Wk = (const float*)d_in[2];
    const float* Wv = (const float*)d_in[3];
    const float* Wo = (const float*)d_in[4];

    float* out      = (float*)d_out;
    float* out_attn = out;                         // [B,S,H]    8388608 f32 (33.55 MB)
    float* out_k    = out + 8388608;               // [B,1,S,HD]  524288 f32
    float* out_v    = out + 8388608 + 524288;      // [B,1,S,HD]  524288 f32

    // Scratch inside d_out's attn region (consumed before gemm_o_mfma writes it):
    bf16* qbuf = (bf16*)d_out;                     // bytes 0..16.78M  roped q bf16
    bf16* kb   = (bf16*)((char*)d_out + 16777216); // bytes ..17.83M   roped k bf16
    bf16* vt   = (bf16*)((char*)d_out + 17825792); // bytes ..18.87M   v^T bf16
    bf16* attn_out = (bf16*)d_ws;                  // [B,S,H] bf16, 16.78 MB

    dim3 blk(256);
    gemm_q_mfma <<<dim3(HID/128, (BB*SEQ)/128), blk, 0, stream>>>(hs, Wq, qbuf);
    gemm_kv_mfma<<<dim3(2,       (BB*SEQ)/128), blk, 0, stream>>>(hs, Wk, Wv, out_k, out_v, kb, vt);
    attn_mfma   <<<dim3(SEQ/64,  NH, BB),       blk, 0, stream>>>(qbuf, kb, vt, attn_out);
    gemm_o_mfma <<<dim3(HID/128, (BB*SEQ)/128), blk, 0, stream>>>(attn_out, Wo, out_attn);
}

// Round 5
// 405.859 us; speedup vs baseline: 1.3504x; 1.1888x over previous
//
#include <hip/hip_runtime.h>
#include <hip/hip_bf16.h>

typedef __hip_bfloat16 bf16;

#define NH   16
#define HD   128
#define SEQ  2048
#define BB   2
#define HID  2048

// ln(10000)/64
#define ROPE_C 0.14391156856f

using frag  = __attribute__((ext_vector_type(8))) short;   // 8 bf16 = 4 VGPRs
using f32x4 = __attribute__((ext_vector_type(4))) float;

// ---------- helpers ----------

// pack 8 fp32 -> 8 bf16 (one 16B LDS write)
__device__ __forceinline__ void cvt8_store(const float4 f0, const float4 f1, bf16* dst) {
    union { frag v; bf16 h[8]; } p;
    p.h[0] = __float2bfloat16(f0.x); p.h[1] = __float2bfloat16(f0.y);
    p.h[2] = __float2bfloat16(f0.z); p.h[3] = __float2bfloat16(f0.w);
    p.h[4] = __float2bfloat16(f1.x); p.h[5] = __float2bfloat16(f1.y);
    p.h[6] = __float2bfloat16(f1.z); p.h[7] = __float2bfloat16(f1.w);
    *reinterpret_cast<frag*>(dst) = p.v;
}

// pack 2 fp32 -> 1 dword of 2 bf16
__device__ __forceinline__ unsigned pk2(float a, float b) {
    union { bf16 h[2]; unsigned u; } p;
    p.h[0] = __float2bfloat16(a);
    p.h[1] = __float2bfloat16(b);
    return p.u;
}

// ---------- fused Q/K/V projection, 8-wave 128x128 tiles ----------
// grid (18, 32): x<16 -> Q col-tile x (with RoPE); x==16 -> K (RoPE + fp32 out
// + bf16 mirror); x==17 -> V (fp32 out + bf16 transposed mirror).
// 512 threads = 8 waves, each wave owns 16 rows x 128 cols (acc[8]).
// 576 blocks -> ~2.25 blocks/CU -> ~16-18 waves/CU (was 8 with 4-wave blocks).
__global__ __launch_bounds__(512) void gemm_qkv(const float* __restrict__ A,
                                                const float* __restrict__ Wq,
                                                const float* __restrict__ Wk,
                                                const float* __restrict__ Wv,
                                                bf16* __restrict__ qout,
                                                float* __restrict__ Ck,
                                                float* __restrict__ Cv,
                                                bf16* __restrict__ kb,
                                                bf16* __restrict__ vt) {
    __shared__ bf16 Asl[4096];   // 128 rows x 32 k (bf16)
    __shared__ bf16 Bsl[4096];
    const int tid  = threadIdx.x;
    const int wave = tid >> 6;
    const int lane = tid & 63;
    const int quad = lane >> 4;
    const int l15  = lane & 15;
    const int row0 = blockIdx.y * 128;
    const int bx   = blockIdx.x;
    const bool isq  = bx < 16;
    const bool is_v = (bx == 17);
    const float* W  = isq ? Wq : (is_v ? Wv : Wk);
    const int col0  = isq ? bx * 128 : 0;

    // staging: thread stages one 8-elem chunk of A and of B per K-step
    const int sr = tid >> 2;          // 0..127
    const int sc = (tid & 3) * 8;     // 0,8,16,24

    f32x4 acc[8];
#pragma unroll
    for (int j = 0; j < 8; ++j) acc[j] = (f32x4){0.f,0.f,0.f,0.f};

    for (int k0 = 0; k0 < HID; k0 += 32) {
        __syncthreads();
        {
            const float4* a0 = reinterpret_cast<const float4*>(A + (size_t)(row0 + sr) * HID + k0 + sc);
            const float4* b0 = reinterpret_cast<const float4*>(W + (size_t)(col0 + sr) * HID + k0 + sc);
            cvt8_store(a0[0], a0[1], &Asl[tid * 8]);
            cvt8_store(b0[0], b0[1], &Bsl[tid * 8]);
        }
        __syncthreads();
        frag af, bfr[8];
        af = *reinterpret_cast<const frag*>(&Asl[(((wave*16 + l15)*4) + quad) * 8]);
#pragma unroll
        for (int j = 0; j < 8; ++j)
            bfr[j] = *reinterpret_cast<const frag*>(&Bsl[(((j*16 + l15)*4) + quad) * 8]);
#pragma unroll
        for (int j = 0; j < 8; ++j)
            acc[j] = __builtin_amdgcn_mfma_f32_16x16x32_bf16(af, bfr[j], acc[j], 0, 0, 0);
    }

    if (isq) {
#pragma unroll
        for (int r = 0; r < 4; ++r) {
            const int row = row0 + wave*16 + quad*4 + r;
            const int s = row & (SEQ - 1);
            bf16* crow = qout + (size_t)row * HID + col0;
#pragma unroll
            for (int j = 0; j < 4; ++j) {
                const int d = 16*j + l15;
                const float invf = expf(-(float)d * ROPE_C);
                float sn, cs;
                sincosf((float)s * invf, &sn, &cs);
                const float x1 = acc[j][r], x2 = acc[j+4][r];
                crow[d]      = __float2bfloat16(x1*cs - x2*sn);
                crow[d + 64] = __float2bfloat16(x2*cs + x1*sn);
            }
        }
    } else if (is_v) {
#pragma unroll
        for (int r = 0; r < 4; ++r) {
            const int row = row0 + wave*16 + quad*4 + r;   // b*SEQ + s
            const int s = row & (SEQ - 1);
            const int b = row >> 11;
            float* crow = Cv + (size_t)row * HD;
#pragma unroll
            for (int j = 0; j < 8; ++j) {
                const int d = 16*j + l15;
                const float val = acc[j][r];
                crow[d] = val;
                vt[((size_t)b * HD + d) * SEQ + s] = __float2bfloat16(val);
            }
        }
    } else {
#pragma unroll
        for (int r = 0; r < 4; ++r) {
            const int row = row0 + wave*16 + quad*4 + r;
            const int s = row & (SEQ - 1);
            float* crow = Ck + (size_t)row * HD;
#pragma unroll
            for (int j = 0; j < 4; ++j) {
                const int d = 16*j + l15;
                const float invf = expf(-(float)d * ROPE_C);
                float sn, cs;
                sincosf((float)s * invf, &sn, &cs);
                const float y1 = acc[j][r]*cs - acc[j+4][r]*sn;
                const float y2 = acc[j+4][r]*cs + acc[j][r]*sn;
                crow[d]      = y1;
                crow[d + 64] = y2;
                kb[(size_t)row * HD + d]      = __float2bfloat16(y1);
                kb[(size_t)row * HD + d + 64] = __float2bfloat16(y2);
            }
        }
    }
}

// ---------- flash MFMA attention, S^T formulation (unchanged from round 2) ----------
// 64-q-row blocks (1024 blocks = 4/CU, 16 waves/CU). Synchronous
// stage-between-barriers. pi-permuted V^T (zero-shuffle PV), XOR bank swizzle,
// defer-max rescale skip.
__global__ __launch_bounds__(256) void attn_mfma(const bf16* __restrict__ qbuf,
                                                 const bf16* __restrict__ kb,
                                                 const bf16* __restrict__ vt,
                                                 bf16* __restrict__ attn_out) {
    __shared__ bf16 Ks[8192];   // 64 keys x 128 dims, chunked + swizzled
    __shared__ bf16 Vt[8192];   // 128 dims x 64 keys, pi-permuted + swizzled

    const int tid  = threadIdx.x;
    const int wave = tid >> 6;
    const int lane = tid & 63;
    const int quad = lane >> 4;
    const int l15  = lane & 15;
    const int q0   = blockIdx.x * 64;
    const int h    = blockIdx.y;
    const int b    = blockIdx.z;

    const bf16* kbb = kb + (size_t)b * SEQ * HD;
    const bf16* vtb = vt + (size_t)b * HD * SEQ;

    // Q B-operand frags: qfr[c] = Q[qrow=w*16+l15][dims c*32+quad*8..+7]
    frag qfr[4];
    {
        const bf16* qrow = qbuf + ((size_t)(b * SEQ + q0 + wave * 16 + l15)) * HID + h * HD;
#pragma unroll
        for (int c = 0; c < 4; ++c)
            qfr[c] = *reinterpret_cast<const frag*>(qrow + c * 32 + quad * 8);
    }

    // K staging decode: 4 x 16B per thread + swizzle
    int kkey[4], kdim[4], kof[4];
#pragma unroll
    for (int i = 0; i < 4; ++i) {
        const int n = tid + i * 256;
        kkey[i] = ((n >> 2) & 15) + (((n >> 6) & 3) << 4);
        kdim[i] = ((n >> 8) << 5) + ((n & 3) << 3);
        kof[i]  = (n * 16) ^ (((n >> 3) & 7) << 4);
    }
    // V staging decode: 8 x 8B per thread, pi-permuted key order + swizzle
    int vdim[8], vkey[8], vof[8];
#pragma unroll
    for (int i = 0; i < 8; ++i) {
        const int m = tid + i * 256;
        vdim[i] = ((m >> 8) << 4) + ((m >> 3) & 15);
        vkey[i] = (((m >> 7) & 1) << 5) + ((m & 1) << 4) + (((m >> 1) & 3) << 2);
        vof[i]  = (m * 8) ^ (((m >> 4) & 7) << 4);
    }

    // swizzled frag-read base (chunk-independent: chunk*1024 = 0 mod 1024)
    const int rb  = (l15 * 4 + quad) * 16;
    const int rbs = rb ^ (((rb >> 7) & 7) << 4);

    f32x4 oacc[8];
#pragma unroll
    for (int dt = 0; dt < 8; ++dt) oacc[dt] = (f32x4){0.f, 0.f, 0.f, 0.f};
    float mrow = -1e30f;
    float lrow = 0.f;
    const float scale = 0.088388347648318433f;   // 1/sqrt(128)

    for (int t0 = 0; t0 < SEQ; t0 += 64) {
        __syncthreads();
        {
            uint4 krg[4];
            uint2 vrg[8];
#pragma unroll
            for (int i = 0; i < 4; ++i)
                krg[i] = *reinterpret_cast<const uint4*>(kbb + (size_t)(t0 + kkey[i]) * HD + kdim[i]);
#pragma unroll
            for (int i = 0; i < 8; ++i)
                vrg[i] = *reinterpret_cast<const uint2*>(vtb + (size_t)vdim[i] * SEQ + t0 + vkey[i]);
#pragma unroll
            for (int i = 0; i < 4; ++i)
                *reinterpret_cast<uint4*>(reinterpret_cast<char*>(Ks) + kof[i]) = krg[i];
#pragma unroll
            for (int i = 0; i < 8; ++i)
                *reinterpret_cast<uint2*>(reinterpret_cast<char*>(Vt) + vof[i]) = vrg[i];
        }
        __syncthreads();

        // S^T: sacc[t], rows = keys t*16+quad*4+r, col = qrow l15
        f32x4 sacc[4];
#pragma unroll
        for (int t = 0; t < 4; ++t) sacc[t] = (f32x4){0.f,0.f,0.f,0.f};
#pragma unroll
        for (int c = 0; c < 4; ++c) {
            frag kf[4];
#pragma unroll
            for (int t = 0; t < 4; ++t)
                kf[t] = *reinterpret_cast<const frag*>(
                            reinterpret_cast<const char*>(Ks) + (c*4+t)*1024 + rbs);
#pragma unroll
            for (int t = 0; t < 4; ++t)
                sacc[t] = __builtin_amdgcn_mfma_f32_16x16x32_bf16(kf[t], qfr[c], sacc[t], 0, 0, 0);
        }

        // softmax; P^T B-frags are lane-local (pi-permuted PV key order)
        float mx = -1e30f;
#pragma unroll
        for (int t = 0; t < 4; ++t)
#pragma unroll
            for (int r = 0; r < 4; ++r) mx = fmaxf(mx, sacc[t][r]);
        mx = fmaxf(mx, __shfl_xor(mx, 16));
        mx = fmaxf(mx, __shfl_xor(mx, 32));
        const bool skip = (bool)__all(mx - mrow <= 90.0f);   // e^(90*scale) ~ e^8 bound
        const float mn = skip ? mrow : fmaxf(mrow, mx);
        const float al = skip ? 1.f : __expf((mrow - mn) * scale);
        float p[4][4];
        float ps = 0.f;
#pragma unroll
        for (int t = 0; t < 4; ++t)
#pragma unroll
            for (int r = 0; r < 4; ++r) {
                p[t][r] = __expf((sacc[t][r] - mn) * scale);
                ps += p[t][r];
            }
        ps += __shfl_xor(ps, 16);
        ps += __shfl_xor(ps, 32);
        lrow = lrow * al + ps;
        mrow = mn;

        // pb[hh] element j = key 32*hh + 16*(j>>2) + 4*quad + (j&3)
        //                  = p[2*hh + (j>>2)][j&3]  -- own registers, no shuffle
        frag pb[2];
#pragma unroll
        for (int hh = 0; hh < 2; ++hh) {
            union { unsigned u[4]; frag f; } pf;
            pf.u[0] = pk2(p[2*hh][0],   p[2*hh][1]);
            pf.u[1] = pk2(p[2*hh][2],   p[2*hh][3]);
            pf.u[2] = pk2(p[2*hh+1][0], p[2*hh+1][1]);
            pf.u[3] = pk2(p[2*hh+1][2], p[2*hh+1][3]);
            pb[hh] = pf.f;
        }

        // rescale O^T accumulators (skipped when max growth deferred)
        if (!skip)
#pragma unroll
            for (int dt = 0; dt < 8; ++dt)
#pragma unroll
                for (int r = 0; r < 4; ++r) oacc[dt][r] *= al;

        // O^T += V^T P^T   (V^T LDS already in pi key order)
#pragma unroll
        for (int dt = 0; dt < 8; ++dt) {
            frag v0 = *reinterpret_cast<const frag*>(
                          reinterpret_cast<const char*>(Vt) + (dt*2+0)*1024 + rbs);
            frag v1 = *reinterpret_cast<const frag*>(
                          reinterpret_cast<const char*>(Vt) + (dt*2+1)*1024 + rbs);
            oacc[dt] = __builtin_amdgcn_mfma_f32_16x16x32_bf16(v0, pb[0], oacc[dt], 0, 0, 0);
            oacc[dt] = __builtin_amdgcn_mfma_f32_16x16x32_bf16(v1, pb[1], oacc[dt], 0, 0, 0);
        }
    }

    // epilogue: O^T lane(quad,l15) holds qrow=w*16+l15, dims dt*16+quad*4+r
    {
        const float inv = 1.f / lrow;
        const int s = q0 + wave * 16 + l15;
        bf16* orow = attn_out + ((size_t)(b * SEQ + s)) * HID + h * HD;
#pragma unroll
        for (int dt = 0; dt < 8; ++dt) {
            uint2 val;
            val.x = pk2(oacc[dt][0] * inv, oacc[dt][1] * inv);
            val.y = pk2(oacc[dt][2] * inv, oacc[dt][3] * inv);
            *reinterpret_cast<uint2*>(orow + dt * 16 + quad * 4) = val;
        }
    }
}

// ---------- final projection, 8-wave 128x128 tiles: C(f32) = A(bf16) * Wo(f32)^T ----------
__global__ __launch_bounds__(512) void gemm_o_mfma(const bf16* __restrict__ A,
                                                   const float* __restrict__ W,
                                                   float* __restrict__ C) {
    __shared__ bf16 Asl[4096];
    __shared__ bf16 Bsl[4096];
    const int tid  = threadIdx.x;
    const int wave = tid >> 6;
    const int lane = tid & 63;
    const int quad = lane >> 4;
    const int l15  = lane & 15;
    const int row0 = blockIdx.y * 128;
    const int col0 = blockIdx.x * 128;

    const int sr = tid >> 2;
    const int sc = (tid & 3) * 8;

    f32x4 acc[8];
#pragma unroll
    for (int j = 0; j < 8; ++j) acc[j] = (f32x4){0.f,0.f,0.f,0.f};

    for (int k0 = 0; k0 < HID; k0 += 32) {
        __syncthreads();
        {
            *reinterpret_cast<uint4*>(&Asl[tid * 8]) =
                *reinterpret_cast<const uint4*>(A + (size_t)(row0 + sr) * HID + k0 + sc);
            const float4* b0 = reinterpret_cast<const float4*>(W + (size_t)(col0 + sr) * HID + k0 + sc);
            cvt8_store(b0[0], b0[1], &Bsl[tid * 8]);
        }
        __syncthreads();
        frag af, bfr[8];
        af = *reinterpret_cast<const frag*>(&Asl[(((wave*16 + l15)*4) + quad) * 8]);
#pragma unroll
        for (int j = 0; j < 8; ++j)
            bfr[j] = *reinterpret_cast<const frag*>(&Bsl[(((j*16 + l15)*4) + quad) * 8]);
#pragma unroll
        for (int j = 0; j < 8; ++j)
            acc[j] = __builtin_amdgcn_mfma_f32_16x16x32_bf16(af, bfr[j], acc[j], 0, 0, 0);
    }

#pragma unroll
    for (int r = 0; r < 4; ++r) {
        const int row = row0 + wave*16 + quad*4 + r;
        float* crow = C + (size_t)row * HID + col0;
#pragma unroll
        for (int j = 0; j < 8; ++j)
            crow[16*j + l15] = acc[j][r];
    }
}

// ---------- launch ----------
extern "C" void kernel_launch(void* const* d_in, const int* in_sizes, int n_in,
                              void* d_out, int out_size, void* d_ws, size_t ws_size,
                              hipStream_t stream) {
    const float* hs = (const float*)d_in[0];
    const float* Wq = (const float*)d_in[1];
    const float* Wk = (const float*)d_in[2];
    const float* Wv = (const float*)d_in[3];
    const float* Wo = (const float*)d_in[4];

    float* out      = (float*)d_out;
    float* out_attn = out;                         // [B,S,H]    8388608 f32 (33.55 MB)
    float* out_k    = out + 8388608;               // [B,1,S,HD]  524288 f32
    float* out_v    = out + 8388608 + 524288;      // [B,1,S,HD]  524288 f32

    // Scratch inside d_out's attn region (consumed before gemm_o_mfma writes it):
    bf16* qbuf = (bf16*)d_out;                     // bytes 0..16.78M  roped q bf16
    bf16* kb   = (bf16*)((char*)d_out + 16777216); // bytes ..17.83M   roped k bf16
    bf16* vt   = (bf16*)((char*)d_out + 17825792); // bytes ..18.87M   v^T bf16
    bf16* attn_out = (bf16*)d_ws;                  // [B,S,H] bf16, 16.78 MB

    gemm_qkv  <<<dim3(18, (BB*SEQ)/128), dim3(512), 0, stream>>>(hs, Wq, Wk, Wv,
                                                                 qbuf, out_k, out_v, kb, vt);
    attn_mfma <<<dim3(SEQ/64, NH, BB),   dim3(256), 0, stream>>>(qbuf, kb, vt, attn_out);
    gemm_o_mfma<<<dim3(HID/128, (BB*SEQ)/128), dim3(512), 0, stream>>>(attn_out, Wo, out_attn);
}